// Round 13
// baseline (216.803 us; speedup 1.0000x reference)
//
#include <hip/hip_runtime.h>

// out[b][j] = sum_i spikes[b][i] * W[i][j]
//   spikes [8,8192] f32, W [8192,8192] f32 row-major, out [8,8192] f32.
// History:
//  R1 86us | R2/R3 202-206 (acc array->scratch + atomics) | R4 58.5 | R5 58.2
//  R6/R7 nt partials -> post-timing divergence. nt BANNED on cross-kernel data.
//  R8 73.2 (TLP-starved) | R9 62.1 (issue-width-starved) | R10 59.7 | R11 58.7
//    => plateau ~58 across geometries; marginal traffic cost ~0.02us/MB ->
//       residual is structural (second dispatch + graph serialization).
//  R12 cooperative-kernel fusion: LAUNCH FAILED (hipLaunchCooperativeKernel
//      incompatible with harness graph capture; output untouched). Lesson:
//      only <<<>>> launches here.
//  R13: same fusion via atomic-ticket last-block reduction (G16 pattern):
//      plain partial stores -> __threadfence -> atomicAdd ticket; last block
//      of each column-panel re-fences and reduces its 32 slabs. One dispatch,
//      no spin-waits (no deadlock possible), counters memset per call.

constexpr int N_PREV = 8192;
constexpr int N_HID  = 8192;
constexpr int BATCH  = 8;
constexpr int TPB    = 256;                    // 4 waves
constexpr int COLS_PER_BLOCK = 256;            // 64 lanes * float4
constexpr int KSLAB  = 256;                    // k-rows per block
constexpr int NSLAB  = N_PREV / KSLAB;         // 32 global slabs
constexpr int KWAVE  = KSLAB / 4;              // 64 k-rows per wave
constexpr int OUT_ELEMS = BATCH * N_HID;       // 65536
constexpr int NPANEL = N_HID / COLS_PER_BLOCK; // 32 column panels

#define FMA4(A, S) \
  A.x += (S) * wv.x; A.y += (S) * wv.y; A.z += (S) * wv.z; A.w += (S) * wv.w;

template <bool USE_ATOMIC>
__global__ __launch_bounds__(TPB, 4) void snn_fused(
    const float* __restrict__ spikes,
    const float* __restrict__ W,
    float* __restrict__ partial,       // [NSLAB][OUT_ELEMS] (unused if atomic)
    int* __restrict__ counters,        // [NPANEL], zeroed per call
    float* __restrict__ out) {
  // 32KB dual-purpose: spikes chunk during K-loop, then per-wave partials.
  __shared__ float smem[4 * BATCH * COLS_PER_BLOCK];
  __shared__ int s_last;

  const int cb   = blockIdx.x;                 // column panel 0..31
  const int p    = blockIdx.y;                 // k-slab 0..31
  const int col0 = cb * COLS_PER_BLOCK;
  const int w    = threadIdx.x >> 6;           // wave 0..3 (in-block k-split)
  const int lane = threadIdx.x & 63;
  const int k0   = p * KSLAB;

  // ---- Phase 1: slab partial (R11's proven structure) ----
  for (int t = threadIdx.x; t < KSLAB * BATCH; t += TPB) {
    const int k = t >> 3, b = t & 7;
    smem[k * 8 + b] = spikes[b * N_PREV + k0 + k];
  }
  __syncthreads();

  // Named accumulators only (R2/R3 lesson: arrays get demoted to scratch).
  float4 a0 = {0,0,0,0}, a1 = {0,0,0,0}, a2 = {0,0,0,0}, a3 = {0,0,0,0};
  float4 a4 = {0,0,0,0}, a5 = {0,0,0,0}, a6 = {0,0,0,0}, a7 = {0,0,0,0};

  const float* wp = W + (size_t)(k0 + w * KWAVE) * N_HID + col0 + 4 * lane;
  #pragma unroll 8
  for (int k = 0; k < KWAVE; ++k) {
    const float4 wv = *reinterpret_cast<const float4*>(wp);
    wp += N_HID;
    const float4 slo =
        *reinterpret_cast<const float4*>(&smem[(w * KWAVE + k) * 8]);     // bcast
    const float4 shi =
        *reinterpret_cast<const float4*>(&smem[(w * KWAVE + k) * 8 + 4]); // bcast
    FMA4(a0, slo.x) FMA4(a1, slo.y) FMA4(a2, slo.z) FMA4(a3, slo.w)
    FMA4(a4, shi.x) FMA4(a5, shi.y) FMA4(a6, shi.z) FMA4(a7, shi.w)
  }

  __syncthreads();   // spikes region dead; reuse smem for reduction

  #define ST(b, A) \
    *reinterpret_cast<float4*>(&smem[(w * BATCH + (b)) * COLS_PER_BLOCK + 4 * lane]) = A;
  ST(0, a0) ST(1, a1) ST(2, a2) ST(3, a3)
  ST(4, a4) ST(5, a5) ST(6, a6) ST(7, a7)
  #undef ST
  __syncthreads();

  // Reduce 4 waves -> 512 float4 panel-slab partial.
  const float4* s4 = reinterpret_cast<const float4*>(smem);
  #pragma unroll
  for (int i = 0; i < 2; ++i) {
    const int o  = threadIdx.x + TPB * i;      // 0..511
    const int b  = o >> 6, c4 = o & 63;
    const float4 v0 = s4[o], v1 = s4[512 + o], v2 = s4[1024 + o], v3 = s4[1536 + o];
    float4 r;
    r.x = (v0.x + v1.x) + (v2.x + v3.x);
    r.y = (v0.y + v1.y) + (v2.y + v3.y);
    r.z = (v0.z + v1.z) + (v2.z + v3.z);
    r.w = (v0.w + v1.w) + (v2.w + v3.w);
    if constexpr (USE_ATOMIC) {
      float* op = &out[b * N_HID + col0 + 4 * c4];
      atomicAdd(op + 0, r.x); atomicAdd(op + 1, r.y);
      atomicAdd(op + 2, r.z); atomicAdd(op + 3, r.w);
    } else {
      *reinterpret_cast<float4*>(
          &partial[(size_t)p * OUT_ELEMS + b * N_HID + col0 + 4 * c4]) = r;
    }
  }

  if constexpr (!USE_ATOMIC) {
    // ---- Ticket: last slab-block of this panel reduces all 32 slabs ----
    __threadfence();                           // release: partials visible
    if (threadIdx.x == 0) {
      const int old = atomicAdd(&counters[cb], 1);
      s_last = (old == NSLAB - 1);
    }
    __syncthreads();
    if (s_last) {
      __threadfence();                         // acquire: see others' partials
      #pragma unroll
      for (int i = 0; i < 2; ++i) {
        const int o  = threadIdx.x + TPB * i;  // 0..511 within panel
        const int b  = o >> 6, c4 = o & 63;
        const size_t base = (size_t)b * N_HID + col0 + 4 * c4;
        float4 s = {0,0,0,0};
        #pragma unroll 8
        for (int q = 0; q < NSLAB; ++q) {
          const float4 v = *reinterpret_cast<const float4*>(
              &partial[(size_t)q * OUT_ELEMS + base]);
          s.x += v.x; s.y += v.y; s.z += v.z; s.w += v.w;
        }
        *reinterpret_cast<float4*>(&out[base]) = s;
      }
    }
  }
}

extern "C" void kernel_launch(void* const* d_in, const int* in_sizes, int n_in,
                              void* d_out, int out_size, void* d_ws, size_t ws_size,
                              hipStream_t stream) {
  const float* spikes = (const float*)d_in[0];   // [8, 8192]
  const float* W      = (const float*)d_in[1];   // [8192, 8192]
  float* out          = (float*)d_out;           // [8, 8192]
  float* partial      = (float*)d_ws;
  int* counters       = (int*)((char*)d_ws + (size_t)NSLAB * OUT_ELEMS * sizeof(float));

  const size_t need =
      (size_t)NSLAB * OUT_ELEMS * sizeof(float) + NPANEL * sizeof(int);  // 8.4MB+128B
  dim3 grid(NPANEL, NSLAB);                      // (32, 32) = 1024 blocks
  dim3 block(TPB);

  if (ws_size >= need) {
    (void)hipMemsetAsync(counters, 0, NPANEL * sizeof(int), stream);
    snn_fused<false><<<grid, block, 0, stream>>>(spikes, W, partial, counters, out);
  } else {
    // Fallback: atomics into zeroed out (deterministic host-side branch).
    (void)hipMemsetAsync(out, 0, (size_t)out_size * sizeof(float), stream);
    snn_fused<true><<<grid, block, 0, stream>>>(spikes, W, partial, counters, out);
  }
}